// Round 1
// baseline (113.742 us; speedup 1.0000x reference)
//
#include <hip/hip_runtime.h>
#include <hip/hip_bf16.h>
#include <math.h>

#define IN_DIM 256
#define L1_DIM 16

// Kernel 1: per-node projections h1 = relu(z @ w1_l1), h2 = relu(z @ w2_l1).
// One thread per node. Weight addresses are lane-uniform -> s_load (SGPR),
// z row read as float4. 32 accumulators/thread.
__global__ __launch_bounds__(256) void proj_kernel(
    const float* __restrict__ z,
    const float* __restrict__ w1,   // [256][16]
    const float* __restrict__ w2,   // [256][16]
    float* __restrict__ h1,         // [n_nodes][16]
    float* __restrict__ h2,         // [n_nodes][16]
    int n_nodes) {
  int node = blockIdx.x * blockDim.x + threadIdx.x;
  if (node >= n_nodes) return;

  const float4* zr = reinterpret_cast<const float4*>(z + (size_t)node * IN_DIM);

  float acc1[L1_DIM];
  float acc2[L1_DIM];
#pragma unroll
  for (int j = 0; j < L1_DIM; ++j) { acc1[j] = 0.f; acc2[j] = 0.f; }

#pragma unroll 4
  for (int k4 = 0; k4 < IN_DIM / 4; ++k4) {
    float4 zv = zr[k4];
    float zk[4] = {zv.x, zv.y, zv.z, zv.w};
#pragma unroll
    for (int u = 0; u < 4; ++u) {
      int k = k4 * 4 + u;
#pragma unroll
      for (int j = 0; j < L1_DIM; ++j) {
        acc1[j] = fmaf(zk[u], w1[k * L1_DIM + j], acc1[j]);
        acc2[j] = fmaf(zk[u], w2[k * L1_DIM + j], acc2[j]);
      }
    }
  }

  float4* o1 = reinterpret_cast<float4*>(h1 + (size_t)node * L1_DIM);
  float4* o2 = reinterpret_cast<float4*>(h2 + (size_t)node * L1_DIM);
#pragma unroll
  for (int q = 0; q < 4; ++q) {
    float4 a, b;
    a.x = fmaxf(acc1[q * 4 + 0], 0.f);
    a.y = fmaxf(acc1[q * 4 + 1], 0.f);
    a.z = fmaxf(acc1[q * 4 + 2], 0.f);
    a.w = fmaxf(acc1[q * 4 + 3], 0.f);
    b.x = fmaxf(acc2[q * 4 + 0], 0.f);
    b.y = fmaxf(acc2[q * 4 + 1], 0.f);
    b.z = fmaxf(acc2[q * 4 + 2], 0.f);
    b.w = fmaxf(acc2[q * 4 + 3], 0.f);
    o1[q] = a;
    o2[q] = b;
  }
}

// Kernel 2: per-edge scoring.
// s1 = dot(h1[src], w1_l2[t]); s2 = dot(h2[dst], w2_l2[t]); out = sigmoid(s1+s2)
__global__ __launch_bounds__(256) void edge_kernel(
    const int* __restrict__ edge_index,  // [2][n_edges]
    const int* __restrict__ edge_type,   // [n_edges]
    const float* __restrict__ h1,
    const float* __restrict__ h2,
    const float* __restrict__ w1_l2,     // [1000][16]
    const float* __restrict__ w2_l2,     // [1000][16]
    float* __restrict__ out,
    int n_edges) {
  int e = blockIdx.x * blockDim.x + threadIdx.x;
  if (e >= n_edges) return;

  int src = edge_index[e];
  int dst = edge_index[n_edges + e];
  int t = edge_type[e];

  const float4* a = reinterpret_cast<const float4*>(h1 + (size_t)src * L1_DIM);
  const float4* b = reinterpret_cast<const float4*>(h2 + (size_t)dst * L1_DIM);
  const float4* u = reinterpret_cast<const float4*>(w1_l2 + (size_t)t * L1_DIM);
  const float4* v = reinterpret_cast<const float4*>(w2_l2 + (size_t)t * L1_DIM);

  float s = 0.f;
#pragma unroll
  for (int q = 0; q < 4; ++q) {
    float4 av = a[q];
    float4 uv = u[q];
    float4 bv = b[q];
    float4 vv = v[q];
    s = fmaf(av.x, uv.x, s);
    s = fmaf(av.y, uv.y, s);
    s = fmaf(av.z, uv.z, s);
    s = fmaf(av.w, uv.w, s);
    s = fmaf(bv.x, vv.x, s);
    s = fmaf(bv.y, vv.y, s);
    s = fmaf(bv.z, vv.z, s);
    s = fmaf(bv.w, vv.w, s);
  }

  // sigmoid
  out[e] = 1.0f / (1.0f + __expf(-s));
}

extern "C" void kernel_launch(void* const* d_in, const int* in_sizes, int n_in,
                              void* d_out, int out_size, void* d_ws, size_t ws_size,
                              hipStream_t stream) {
  const float* z      = (const float*)d_in[0];
  const int* edge_idx = (const int*)d_in[1];
  const int* edge_typ = (const int*)d_in[2];
  const float* w1_l1  = (const float*)d_in[3];
  const float* w1_l2  = (const float*)d_in[4];
  const float* w2_l1  = (const float*)d_in[5];
  const float* w2_l2  = (const float*)d_in[6];
  float* out = (float*)d_out;

  int n_nodes = in_sizes[0] / IN_DIM;
  int n_edges = in_sizes[2];

  float* h1 = (float*)d_ws;
  float* h2 = h1 + (size_t)n_nodes * L1_DIM;

  {
    int block = 256;
    int grid = (n_nodes + block - 1) / block;
    proj_kernel<<<grid, block, 0, stream>>>(z, w1_l1, w2_l1, h1, h2, n_nodes);
  }
  {
    int block = 256;
    int grid = (n_edges + block - 1) / block;
    edge_kernel<<<grid, block, 0, stream>>>(edge_idx, edge_typ, h1, h2,
                                            w1_l2, w2_l2, out, n_edges);
  }
}

// Round 2
// 77.535 us; speedup vs baseline: 1.4670x; 1.4670x over previous
//
#include <hip/hip_runtime.h>
#include <hip/hip_bf16.h>
#include <math.h>

#define IN_DIM 256
#define L1_DIM 16

// ---------------- proj kernel ----------------
// h1 = relu(z @ w1_l1), h2 = relu(z @ w2_l1), one thread per node.
// z rows staged through LDS with coalesced float4 loads; global loads for
// chunk c+1 issued before computing chunk c (latency hidden under FMAs).
// Weights indexed wave-uniformly -> s_load broadcast (free).
#define NPB 64                 // nodes per block == threads per block
#define KC 64                  // k-chunk size
#define NCHUNK (IN_DIM / KC)   // 4
#define PAD 65                 // LDS row stride in floats (odd -> 2-way banks)
#define F4_PER_THREAD 16       // NPB*KC/4 / NPB

__global__ __launch_bounds__(NPB) void proj_kernel(
    const float* __restrict__ z,
    const float* __restrict__ w1,   // [256][16]
    const float* __restrict__ w2,   // [256][16]
    float* __restrict__ h1,
    float* __restrict__ h2,
    int n_nodes) {
  __shared__ float zs[NPB * PAD];   // 16.6 KB

  const int tid = threadIdx.x;
  const int node0 = blockIdx.x * NPB;
  const int my_node = node0 + tid;

  float4 buf[F4_PER_THREAD];

  float acc1[L1_DIM], acc2[L1_DIM];
#pragma unroll
  for (int j = 0; j < L1_DIM; ++j) { acc1[j] = 0.f; acc2[j] = 0.f; }

  // issue coalesced global loads for chunk c into registers
  auto issue_loads = [&](int c) {
#pragma unroll
    for (int r = 0; r < F4_PER_THREAD; ++r) {
      int i = r * NPB + tid;     // flat float4 slot
      int nd = i >> 4;           // KC/4 = 16 float4 per row
      int c4 = i & 15;
      int ng = node0 + nd;
      if (ng >= n_nodes) ng = n_nodes - 1;   // clamp (stay in-bounds)
      buf[r] = *reinterpret_cast<const float4*>(
          z + (size_t)ng * IN_DIM + c * KC + c4 * 4);
    }
  };
  // scatter registers into LDS (scalar writes: rows padded to 65 floats)
  auto write_lds = [&]() {
#pragma unroll
    for (int r = 0; r < F4_PER_THREAD; ++r) {
      int i = r * NPB + tid;
      int nd = i >> 4;
      int c4 = i & 15;
      float* p = &zs[nd * PAD + c4 * 4];
      p[0] = buf[r].x; p[1] = buf[r].y; p[2] = buf[r].z; p[3] = buf[r].w;
    }
  };

  issue_loads(0);
  write_lds();
  __syncthreads();

  for (int c = 0; c < NCHUNK; ++c) {
    if (c + 1 < NCHUNK) issue_loads(c + 1);   // prefetch next chunk

    const float* zrow = &zs[tid * PAD];
#pragma unroll 4
    for (int k = 0; k < KC; ++k) {
      float zk = zrow[k];
      int kg = c * KC + k;
      const float* w1r = w1 + kg * L1_DIM;   // wave-uniform -> SGPR
      const float* w2r = w2 + kg * L1_DIM;
#pragma unroll
      for (int j = 0; j < L1_DIM; ++j) {
        acc1[j] = fmaf(zk, w1r[j], acc1[j]);
        acc2[j] = fmaf(zk, w2r[j], acc2[j]);
      }
    }

    if (c + 1 < NCHUNK) {
      __syncthreads();   // everyone done reading zs
      write_lds();
      __syncthreads();   // zs ready for next chunk
    }
  }

  if (my_node < n_nodes) {
    float4* o1 = reinterpret_cast<float4*>(h1 + (size_t)my_node * L1_DIM);
    float4* o2 = reinterpret_cast<float4*>(h2 + (size_t)my_node * L1_DIM);
#pragma unroll
    for (int q = 0; q < 4; ++q) {
      float4 a, b;
      a.x = fmaxf(acc1[q * 4 + 0], 0.f);
      a.y = fmaxf(acc1[q * 4 + 1], 0.f);
      a.z = fmaxf(acc1[q * 4 + 2], 0.f);
      a.w = fmaxf(acc1[q * 4 + 3], 0.f);
      b.x = fmaxf(acc2[q * 4 + 0], 0.f);
      b.y = fmaxf(acc2[q * 4 + 1], 0.f);
      b.z = fmaxf(acc2[q * 4 + 2], 0.f);
      b.w = fmaxf(acc2[q * 4 + 3], 0.f);
      o1[q] = a;
      o2[q] = b;
    }
  }
}

// ---------------- edge kernel ----------------
// 4 lanes per edge; lane q reads float4 quarter q of each 64B row ->
// 4 lanes cover one cache line exactly. __shfl_xor reduce within quad.
__global__ __launch_bounds__(256) void edge_kernel(
    const int* __restrict__ edge_index,  // [2][n_edges]
    const int* __restrict__ edge_type,   // [n_edges]
    const float* __restrict__ h1,
    const float* __restrict__ h2,
    const float* __restrict__ w1_l2,     // [1000][16]
    const float* __restrict__ w2_l2,     // [1000][16]
    float* __restrict__ out,
    int n_edges) {
  int tid = blockIdx.x * blockDim.x + threadIdx.x;
  int e = tid >> 2;
  int q = tid & 3;
  if (e >= n_edges) return;

  int src = edge_index[e];
  int dst = edge_index[n_edges + e];
  int t   = edge_type[e];

  const float4 a = *reinterpret_cast<const float4*>(h1    + (size_t)src * L1_DIM + q * 4);
  const float4 b = *reinterpret_cast<const float4*>(h2    + (size_t)dst * L1_DIM + q * 4);
  const float4 u = *reinterpret_cast<const float4*>(w1_l2 + (size_t)t   * L1_DIM + q * 4);
  const float4 v = *reinterpret_cast<const float4*>(w2_l2 + (size_t)t   * L1_DIM + q * 4);

  float s = 0.f;
  s = fmaf(a.x, u.x, s);
  s = fmaf(a.y, u.y, s);
  s = fmaf(a.z, u.z, s);
  s = fmaf(a.w, u.w, s);
  s = fmaf(b.x, v.x, s);
  s = fmaf(b.y, v.y, s);
  s = fmaf(b.z, v.z, s);
  s = fmaf(b.w, v.w, s);

  s += __shfl_xor(s, 1);
  s += __shfl_xor(s, 2);

  if (q == 0) {
    out[e] = 1.0f / (1.0f + __expf(-s));
  }
}

extern "C" void kernel_launch(void* const* d_in, const int* in_sizes, int n_in,
                              void* d_out, int out_size, void* d_ws, size_t ws_size,
                              hipStream_t stream) {
  const float* z      = (const float*)d_in[0];
  const int* edge_idx = (const int*)d_in[1];
  const int* edge_typ = (const int*)d_in[2];
  const float* w1_l1  = (const float*)d_in[3];
  const float* w1_l2  = (const float*)d_in[4];
  const float* w2_l1  = (const float*)d_in[5];
  const float* w2_l2  = (const float*)d_in[6];
  float* out = (float*)d_out;

  int n_nodes = in_sizes[0] / IN_DIM;
  int n_edges = in_sizes[2];

  float* h1 = (float*)d_ws;
  float* h2 = h1 + (size_t)n_nodes * L1_DIM;

  {
    int grid = (n_nodes + NPB - 1) / NPB;
    proj_kernel<<<grid, NPB, 0, stream>>>(z, w1_l1, w2_l1, h1, h2, n_nodes);
  }
  {
    long long threads = (long long)n_edges * 4;
    int block = 256;
    int grid = (int)((threads + block - 1) / block);
    edge_kernel<<<grid, block, 0, stream>>>(edge_idx, edge_typ, h1, h2,
                                            w1_l2, w2_l2, out, n_edges);
  }
}

// Round 3
// 57.250 us; speedup vs baseline: 1.9868x; 1.3543x over previous
//
#include <hip/hip_runtime.h>
#include <hip/hip_bf16.h>
#include <math.h>

#define IN_DIM 256
#define L1_DIM 16

// ---------------- proj kernel ----------------
// Block = 256 threads = 4 waves over a 64-node tile.
// Wave w owns output group: (w<2 ? w1 : w2), j-half (w&1)*8. Lane = node.
// Weights are wave-uniform -> s_load broadcast. z tile double-buffered in
// LDS, row stride 65 (odd mod 32 -> 2-way bank access = free).
#define NPB 64                  // nodes per block
#define KC 64                   // k-chunk
#define NCHUNK (IN_DIM / KC)    // 4
#define ZSTRIDE 65
#define BLOCK 256
#define F4PT 4                  // float4 staging loads per thread per chunk

__global__ __launch_bounds__(BLOCK) void proj_kernel(
    const float* __restrict__ z,
    const float* __restrict__ w1,   // [256][16]
    const float* __restrict__ w2,   // [256][16]
    float* __restrict__ h1,
    float* __restrict__ h2,
    int n_nodes) {
  __shared__ float zs[2][NPB * ZSTRIDE];   // 33.3 KB

  const int tid  = threadIdx.x;
  const int lane = tid & 63;
  const int wv   = __builtin_amdgcn_readfirstlane(tid >> 6);
  const int node0 = blockIdx.x * NPB;

  const float* wsel = (wv < 2) ? w1 : w2;
  float*       hsel = (wv < 2) ? h1 : h2;
  const int jbase = (wv & 1) * 8;

  float acc[8];
#pragma unroll
  for (int j = 0; j < 8; ++j) acc[j] = 0.f;

  float4 buf[F4PT];

  // coalesced global -> regs for chunk c
  auto issue = [&](int c) {
#pragma unroll
    for (int r = 0; r < F4PT; ++r) {
      int slot = r * BLOCK + tid;    // 0..1023 float4 slots
      int nd = slot >> 4;            // 16 float4 per 64-float row chunk
      int c4 = slot & 15;
      int ng = node0 + nd;
      if (ng >= n_nodes) ng = n_nodes - 1;  // clamp, stay in bounds
      buf[r] = *reinterpret_cast<const float4*>(
          z + (size_t)ng * IN_DIM + c * KC + c4 * 4);
    }
  };
  // regs -> LDS buffer b (stride-65 rows; scalar writes are 2-way = free)
  auto lwrite = [&](int b) {
#pragma unroll
    for (int r = 0; r < F4PT; ++r) {
      int slot = r * BLOCK + tid;
      int nd = slot >> 4;
      int c4 = slot & 15;
      float* p = &zs[b][nd * ZSTRIDE + c4 * 4];
      p[0] = buf[r].x; p[1] = buf[r].y; p[2] = buf[r].z; p[3] = buf[r].w;
    }
  };

  issue(0);
  lwrite(0);
  __syncthreads();

#pragma unroll
  for (int c = 0; c < NCHUNK; ++c) {
    if (c + 1 < NCHUNK) issue(c + 1);   // prefetch next chunk into regs

    const float* zrow = &zs[c & 1][lane * ZSTRIDE];
#pragma unroll 4
    for (int k = 0; k < KC; ++k) {
      float zk = zrow[k];
      const float* wr = wsel + (size_t)(c * KC + k) * L1_DIM + jbase; // uniform
#pragma unroll
      for (int j = 0; j < 8; ++j) acc[j] = fmaf(zk, wr[j], acc[j]);
    }

    if (c + 1 < NCHUNK) {
      lwrite((c + 1) & 1);   // other buffer; prior barrier protects it
      __syncthreads();
    }
  }

  int node = node0 + lane;
  if (node < n_nodes) {
    float4 o0, o1;
    o0.x = fmaxf(acc[0], 0.f);
    o0.y = fmaxf(acc[1], 0.f);
    o0.z = fmaxf(acc[2], 0.f);
    o0.w = fmaxf(acc[3], 0.f);
    o1.x = fmaxf(acc[4], 0.f);
    o1.y = fmaxf(acc[5], 0.f);
    o1.z = fmaxf(acc[6], 0.f);
    o1.w = fmaxf(acc[7], 0.f);
    float* hp = hsel + (size_t)node * L1_DIM + jbase;
    *reinterpret_cast<float4*>(hp)     = o0;
    *reinterpret_cast<float4*>(hp + 4) = o1;
  }
}

// ---------------- edge kernel ----------------
// 4 lanes per edge; lane q reads float4 quarter q of each 64B row ->
// 4 lanes cover one cache line exactly. __shfl_xor reduce within quad.
__global__ __launch_bounds__(256) void edge_kernel(
    const int* __restrict__ edge_index,  // [2][n_edges]
    const int* __restrict__ edge_type,   // [n_edges]
    const float* __restrict__ h1,
    const float* __restrict__ h2,
    const float* __restrict__ w1_l2,     // [1000][16]
    const float* __restrict__ w2_l2,     // [1000][16]
    float* __restrict__ out,
    int n_edges) {
  int tid = blockIdx.x * blockDim.x + threadIdx.x;
  int e = tid >> 2;
  int q = tid & 3;
  if (e >= n_edges) return;

  int src = edge_index[e];
  int dst = edge_index[n_edges + e];
  int t   = edge_type[e];

  const float4 a = *reinterpret_cast<const float4*>(h1    + (size_t)src * L1_DIM + q * 4);
  const float4 b = *reinterpret_cast<const float4*>(h2    + (size_t)dst * L1_DIM + q * 4);
  const float4 u = *reinterpret_cast<const float4*>(w1_l2 + (size_t)t   * L1_DIM + q * 4);
  const float4 v = *reinterpret_cast<const float4*>(w2_l2 + (size_t)t   * L1_DIM + q * 4);

  float s = 0.f;
  s = fmaf(a.x, u.x, s);
  s = fmaf(a.y, u.y, s);
  s = fmaf(a.z, u.z, s);
  s = fmaf(a.w, u.w, s);
  s = fmaf(b.x, v.x, s);
  s = fmaf(b.y, v.y, s);
  s = fmaf(b.z, v.z, s);
  s = fmaf(b.w, v.w, s);

  s += __shfl_xor(s, 1);
  s += __shfl_xor(s, 2);

  if (q == 0) {
    out[e] = 1.0f / (1.0f + __expf(-s));
  }
}

extern "C" void kernel_launch(void* const* d_in, const int* in_sizes, int n_in,
                              void* d_out, int out_size, void* d_ws, size_t ws_size,
                              hipStream_t stream) {
  const float* z      = (const float*)d_in[0];
  const int* edge_idx = (const int*)d_in[1];
  const int* edge_typ = (const int*)d_in[2];
  const float* w1_l1  = (const float*)d_in[3];
  const float* w1_l2  = (const float*)d_in[4];
  const float* w2_l1  = (const float*)d_in[5];
  const float* w2_l2  = (const float*)d_in[6];
  float* out = (float*)d_out;

  int n_nodes = in_sizes[0] / IN_DIM;
  int n_edges = in_sizes[2];

  float* h1 = (float*)d_ws;
  float* h2 = h1 + (size_t)n_nodes * L1_DIM;

  {
    int grid = (n_nodes + NPB - 1) / NPB;
    proj_kernel<<<grid, BLOCK, 0, stream>>>(z, w1_l1, w2_l1, h1, h2, n_nodes);
  }
  {
    long long threads = (long long)n_edges * 4;
    int block = 256;
    int grid = (int)((threads + block - 1) / block);
    edge_kernel<<<grid, block, 0, stream>>>(edge_idx, edge_typ, h1, h2,
                                            w1_l2, w2_l2, out, n_edges);
  }
}